// Round 1
// baseline (1841.289 us; speedup 1.0000x reference)
//
#include <hip/hip_runtime.h>
#include <hip/hip_bf16.h>
#include <math.h>

// Edge_Encoder_Residual: 2-layer GATv2 on line-graph + time-MLP + decoder.
// N = in_sizes[0]/16 nodes, E = in_sizes[1]/2 edges, Et = E + N (self loops).
// Layout: all fp32. H=2 heads, C=32, HC=64.

#define BLK 256

__device__ __forceinline__ float leaky02(float x) { return x >= 0.f ? x : 0.2f * x; }
__device__ __forceinline__ float relu(float x) { return x > 0.f ? x : 0.f; }

// exact float atomic max via sign-magnitude ordered int trick
__device__ __forceinline__ void atomicMaxFloat(float* addr, float val) {
    if (val >= 0.f) {
        atomicMax((int*)addr, __float_as_int(val));
    } else {
        atomicMin((unsigned int*)addr, __float_as_uint(val));
    }
}

// ---------- tiny: time embedding + MLP + collapsed decoder matrices ----------
__global__ void k_tiny(const int* __restrict__ t,
                       const float* __restrict__ Wt0, const float* __restrict__ bt0,
                       const float* __restrict__ Wt1, const float* __restrict__ bt1,
                       const float* __restrict__ Wfd, const float* __restrict__ bfd,
                       const float* __restrict__ Wcls, const float* __restrict__ bcls,
                       float* __restrict__ wcomb,   // [96][2]
                       float* __restrict__ bfinal)  // [2]
{
    __shared__ float temb[16];
    int tid = threadIdx.x;
    if (tid == 0) {
        float tf = (float)t[0];  // * (1000/MAX_TIME) == *1
        float e0[16], v1[16];
        const float cexp = -logf(10000.f) / 7.f;
        for (int j = 0; j < 8; ++j) {
            float ang = tf * expf((float)j * cexp);
            e0[j] = sinf(ang);
            e0[8 + j] = cosf(ang);
        }
        for (int i = 0; i < 16; ++i) {
            float a = bt0[i];
            for (int j = 0; j < 16; ++j) a += e0[j] * Wt0[j * 16 + i];
            v1[i] = a / (1.f + expf(-a));  // silu
        }
        for (int i = 0; i < 16; ++i) {
            float a = bt1[i];
            for (int j = 0; j < 16; ++j) a += v1[j] * Wt1[j * 16 + i];
            temb[i] = a / (1.f + expf(-a));
        }
    }
    __syncthreads();
    if (tid < 192) {  // wcomb[i][k] = sum_j Wfd[i][j] * Wcls[j][k]
        int i = tid >> 1, k = tid & 1;
        float a = 0.f;
        for (int j = 0; j < 32; ++j) a += Wfd[i * 32 + j] * Wcls[j * 2 + k];
        wcomb[tid] = a;
    }
    __syncthreads();
    if (tid < 2) {  // bias + time contribution (node-constant)
        float a = bcls[tid];
        for (int j = 0; j < 32; ++j) a += bfd[j] * Wcls[j * 2 + tid];
        for (int d = 0; d < 16; ++d) a += temb[d] * wcomb[(64 + d) * 2 + tid];
        bfinal[tid] = a;
    }
}

// ---------- layer 0 node precompute: xl = x@Wl+bl, xr = x@Wr+br, res = relu(x@Wres+bres)
__global__ void k_pre0(const float* __restrict__ x,
                       const float* __restrict__ Wl, const float* __restrict__ bl,
                       const float* __restrict__ Wr, const float* __restrict__ br,
                       const float* __restrict__ Wres, const float* __restrict__ bres,
                       float* __restrict__ xl, float* __restrict__ xr, float* __restrict__ res,
                       int N)
{
    int gid = blockIdx.x * BLK + threadIdx.x;
    if (gid >= N * 64) return;
    int n = gid >> 6, c = gid & 63;
    const float* xrow = x + (size_t)n * 16;
    float al = bl[c], ar = br[c], ares = bres[c];
    #pragma unroll
    for (int k = 0; k < 16; ++k) {
        float xv = xrow[k];
        al += xv * Wl[k * 64 + c];
        ar += xv * Wr[k * 64 + c];
        ares += xv * Wres[k * 64 + c];
    }
    xl[gid] = al;
    xr[gid] = ar;
    res[gid] = relu(ares);
}

// ---------- layer 1 node precompute (64->64, no bias on xl/xr) ----------
__global__ void k_pre1(const float* __restrict__ h,
                       const float* __restrict__ Wl, const float* __restrict__ Wr,
                       const float* __restrict__ Wres, const float* __restrict__ bres,
                       float* __restrict__ xl, float* __restrict__ xr, float* __restrict__ res,
                       int N)
{
    int gid = blockIdx.x * BLK + threadIdx.x;
    if (gid >= N * 64) return;
    int n = gid >> 6, c = gid & 63;
    const float* hrow = h + (size_t)n * 64;
    float al = 0.f, ar = 0.f, ares = bres[c];
    #pragma unroll 8
    for (int k = 0; k < 64; ++k) {
        float hv = hrow[k];
        al += hv * Wl[k * 64 + c];
        ar += hv * Wr[k * 64 + c];
        ares += hv * Wres[k * 64 + c];
    }
    xl[gid] = al;
    xr[gid] = ar;
    res[gid] = relu(ares);
}

// ---------- init accumulators ----------
__global__ void k_init(float* __restrict__ acc, float* __restrict__ den, float* __restrict__ m, int N)
{
    int gid = blockIdx.x * BLK + threadIdx.x;
    if (gid < N * 64) acc[gid] = 0.f;
    if (gid < N * 2) { den[gid] = 0.f; m[gid] = -INFINITY; }
}

// ---------- pass 1: logits + segment max ----------
__global__ void k_pass1(const int* __restrict__ ei, int E, int Et,
                        const float* __restrict__ xl, const float* __restrict__ xr,
                        const float* __restrict__ att,
                        float* __restrict__ lgt, float* __restrict__ m)
{
    int gid = blockIdx.x * BLK + threadIdx.x;
    int edge = gid >> 6, c = gid & 63;
    if (edge >= Et) return;
    int s, d;
    if (edge < E) { s = ei[edge]; d = ei[E + edge]; }
    else { s = edge - E; d = s; }
    float v = leaky02(xl[(size_t)s * 64 + c] + xr[(size_t)d * 64 + c]) * att[c];
    // reduce over 32 lanes (one head per half-wave)
    #pragma unroll
    for (int off = 16; off >= 1; off >>= 1) v += __shfl_xor(v, off, 32);
    if ((c & 31) == 0) {
        int hh = c >> 5;
        lgt[(size_t)edge * 2 + hh] = v;
        atomicMaxFloat(&m[(size_t)d * 2 + hh], v);
    }
}

// ---------- pass 2: exp-weighted scatter ----------
__global__ void k_pass2(const int* __restrict__ ei, int E, int Et,
                        const float* __restrict__ xl,
                        const float* __restrict__ lgt, const float* __restrict__ m,
                        float* __restrict__ den, float* __restrict__ acc)
{
    int gid = blockIdx.x * BLK + threadIdx.x;
    int edge = gid >> 6, c = gid & 63;
    if (edge >= Et) return;
    int s, d;
    if (edge < E) { s = ei[edge]; d = ei[E + edge]; }
    else { s = edge - E; d = s; }
    int hh = c >> 5;
    float ex = __expf(lgt[(size_t)edge * 2 + hh] - m[(size_t)d * 2 + hh]);
    if ((c & 31) == 0) atomicAdd(&den[(size_t)d * 2 + hh], ex);
    atomicAdd(&acc[(size_t)d * 64 + c], ex * xl[(size_t)s * 64 + c]);
}

// ---------- finalize: h = relu(acc/den (+bias)) + res ----------
__global__ void k_fin(const float* __restrict__ acc, const float* __restrict__ den,
                      const float* __restrict__ bias,  // may be null
                      const float* __restrict__ res,
                      float* __restrict__ hout, int N)
{
    int gid = blockIdx.x * BLK + threadIdx.x;
    if (gid >= N * 64) return;
    int n = gid >> 6, c = gid & 63;
    float v = acc[gid] / (den[(size_t)n * 2 + (c >> 5)] + 1e-16f);
    if (bias) v += bias[c];
    hout[gid] = relu(v) + res[gid];
}

// ---------- decoder ----------
__global__ void k_dec(const float* __restrict__ h, const float* __restrict__ cond,
                      const float* __restrict__ wcomb, const float* __restrict__ bfinal,
                      float* __restrict__ out, int N)
{
    int n = blockIdx.x * BLK + threadIdx.x;
    if (n >= N) return;
    float o0 = bfinal[0], o1 = bfinal[1];
    const float* hrow = h + (size_t)n * 64;
    #pragma unroll 8
    for (int c = 0; c < 64; ++c) {
        float hv = hrow[c];
        o0 += hv * wcomb[c * 2];
        o1 += hv * wcomb[c * 2 + 1];
    }
    const float* crow = cond + (size_t)n * 16;
    #pragma unroll
    for (int d = 0; d < 16; ++d) {
        float cv = crow[d];
        o0 += cv * wcomb[(80 + d) * 2];
        o1 += cv * wcomb[(80 + d) * 2 + 1];
    }
    out[(size_t)n * 2] = o0;
    out[(size_t)n * 2 + 1] = o1;
}

static inline int gblk(long long threads) { return (int)((threads + BLK - 1) / BLK); }

extern "C" void kernel_launch(void* const* d_in, const int* in_sizes, int n_in,
                              void* d_out, int out_size, void* d_ws, size_t ws_size,
                              hipStream_t stream) {
    const float* x     = (const float*)d_in[0];
    const int*   ei    = (const int*)d_in[1];
    const int*   t     = (const int*)d_in[2];
    const float* cond  = (const float*)d_in[3];
    const float* Wl0   = (const float*)d_in[4];
    const float* bl0   = (const float*)d_in[5];
    const float* Wr0   = (const float*)d_in[6];
    const float* br0   = (const float*)d_in[7];
    const float* att0  = (const float*)d_in[8];
    const float* bias0 = (const float*)d_in[9];
    const float* Wres0 = (const float*)d_in[10];
    const float* bres0 = (const float*)d_in[11];
    const float* Wl1   = (const float*)d_in[12];
    const float* Wr1   = (const float*)d_in[13];
    const float* att1  = (const float*)d_in[14];
    const float* Wres1 = (const float*)d_in[15];
    const float* bres1 = (const float*)d_in[16];
    const float* Wt0   = (const float*)d_in[17];
    const float* bt0   = (const float*)d_in[18];
    const float* Wt1   = (const float*)d_in[19];
    const float* bt1   = (const float*)d_in[20];
    const float* Wfd   = (const float*)d_in[21];
    const float* bfd   = (const float*)d_in[22];
    const float* Wcls  = (const float*)d_in[23];
    const float* bcls  = (const float*)d_in[24];
    float* out = (float*)d_out;

    const int N  = in_sizes[0] / 16;
    const int E  = in_sizes[1] / 2;
    const int Et = E + N;

    float* ws = (float*)d_ws;
    size_t o = 0;
    float* xl    = ws + o; o += (size_t)N * 64;
    float* xr    = ws + o; o += (size_t)N * 64;
    float* res   = ws + o; o += (size_t)N * 64;
    float* hbuf  = ws + o; o += (size_t)N * 64;
    float* acc   = ws + o; o += (size_t)N * 64;
    float* lgt   = ws + o; o += (size_t)Et * 2;
    float* m     = ws + o; o += (size_t)N * 2;
    float* den   = ws + o; o += (size_t)N * 2;
    float* wcomb = ws + o; o += 192;
    float* bfin  = ws + o; o += 2;

    // tiny decoder/time precompute
    k_tiny<<<1, BLK, 0, stream>>>(t, Wt0, bt0, Wt1, bt1, Wfd, bfd, Wcls, bcls, wcomb, bfin);

    // ---- layer 0 ----
    k_pre0<<<gblk((long long)N * 64), BLK, 0, stream>>>(x, Wl0, bl0, Wr0, br0, Wres0, bres0, xl, xr, res, N);
    k_init<<<gblk((long long)N * 64), BLK, 0, stream>>>(acc, den, m, N);
    k_pass1<<<gblk((long long)Et * 64), BLK, 0, stream>>>(ei, E, Et, xl, xr, att0, lgt, m);
    k_pass2<<<gblk((long long)Et * 64), BLK, 0, stream>>>(ei, E, Et, xl, lgt, m, den, acc);
    k_fin<<<gblk((long long)N * 64), BLK, 0, stream>>>(acc, den, bias0, res, hbuf, N);

    // ---- layer 1 ----
    k_pre1<<<gblk((long long)N * 64), BLK, 0, stream>>>(hbuf, Wl1, Wr1, Wres1, bres1, xl, xr, res, N);
    k_init<<<gblk((long long)N * 64), BLK, 0, stream>>>(acc, den, m, N);
    k_pass1<<<gblk((long long)Et * 64), BLK, 0, stream>>>(ei, E, Et, xl, xr, att1, lgt, m);
    k_pass2<<<gblk((long long)Et * 64), BLK, 0, stream>>>(ei, E, Et, xl, lgt, m, den, acc);
    k_fin<<<gblk((long long)N * 64), BLK, 0, stream>>>(acc, den, nullptr, res, hbuf, N);

    // ---- decoder ----
    k_dec<<<gblk(N), BLK, 0, stream>>>(hbuf, cond, wcomb, bfin, out, N);
}

// Round 2
// 872.241 us; speedup vs baseline: 2.1110x; 2.1110x over previous
//
#include <hip/hip_runtime.h>
#include <hip/hip_bf16.h>
#include <math.h>

// Edge_Encoder_Residual: 2-layer GATv2 on line-graph + time-MLP + decoder.
// Round 2: CSR (group edges by dst) + fused gather-style GATv2 layer with
// online softmax (one wave of 64 lanes per destination node, lane = channel,
// half-wave = head). Eliminates the 435MB/dispatch f32 atomic scatter storm.

#define BLK 256

__device__ __forceinline__ float leaky02(float x) { return x >= 0.f ? x : 0.2f * x; }
__device__ __forceinline__ float relu(float x) { return x > 0.f ? x : 0.f; }

// ---------- tiny: time embedding + MLP + collapsed decoder matrices ----------
__global__ void k_tiny(const int* __restrict__ t,
                       const float* __restrict__ Wt0, const float* __restrict__ bt0,
                       const float* __restrict__ Wt1, const float* __restrict__ bt1,
                       const float* __restrict__ Wfd, const float* __restrict__ bfd,
                       const float* __restrict__ Wcls, const float* __restrict__ bcls,
                       float* __restrict__ wcomb,   // [96][2]
                       float* __restrict__ bfinal)  // [2]
{
    __shared__ float temb[16];
    int tid = threadIdx.x;
    if (tid == 0) {
        float tf = (float)t[0];  // * (1000/MAX_TIME) == *1
        float e0[16], v1[16];
        const float cexp = -logf(10000.f) / 7.f;
        for (int j = 0; j < 8; ++j) {
            float ang = tf * expf((float)j * cexp);
            e0[j] = sinf(ang);
            e0[8 + j] = cosf(ang);
        }
        for (int i = 0; i < 16; ++i) {
            float a = bt0[i];
            for (int j = 0; j < 16; ++j) a += e0[j] * Wt0[j * 16 + i];
            v1[i] = a / (1.f + expf(-a));  // silu
        }
        for (int i = 0; i < 16; ++i) {
            float a = bt1[i];
            for (int j = 0; j < 16; ++j) a += v1[j] * Wt1[j * 16 + i];
            temb[i] = a / (1.f + expf(-a));
        }
    }
    __syncthreads();
    if (tid < 192) {  // wcomb[i][k] = sum_j Wfd[i][j] * Wcls[j][k]
        int i = tid >> 1, k = tid & 1;
        float a = 0.f;
        for (int j = 0; j < 32; ++j) a += Wfd[i * 32 + j] * Wcls[j * 2 + k];
        wcomb[tid] = a;
    }
    __syncthreads();
    if (tid < 2) {  // bias + time contribution (node-constant)
        float a = bcls[tid];
        for (int j = 0; j < 32; ++j) a += bfd[j] * Wcls[j * 2 + tid];
        for (int d = 0; d < 16; ++d) a += temb[d] * wcomb[(64 + d) * 2 + tid];
        bfinal[tid] = a;
    }
}

// ---------- CSR build ----------
__global__ void k_zero(int* __restrict__ cnt, int* __restrict__ total, int N)
{
    int gid = blockIdx.x * BLK + threadIdx.x;
    if (gid < N) cnt[gid] = 0;
    if (gid == 0) *total = 0;
}

__global__ void k_hist(const int* __restrict__ ei, int E, int* __restrict__ cnt)
{
    int e = blockIdx.x * BLK + threadIdx.x;
    if (e < E) atomicAdd(&cnt[ei[E + e]], 1);
}

// per-node base offset: wave-aggregated atomic bump of a single counter.
// Segment ranges are disjoint; their order in memory is irrelevant.
__global__ void k_base(const int* __restrict__ cnt, int* __restrict__ rowptr,
                       int* __restrict__ wr, int* __restrict__ total, int N)
{
    int gid = blockIdx.x * BLK + threadIdx.x;
    int lane = threadIdx.x & 63;
    int c = (gid < N) ? cnt[gid] : 0;
    int incl = c;
    #pragma unroll
    for (int off = 1; off < 64; off <<= 1) {
        int tv = __shfl_up(incl, off, 64);
        if (lane >= off) incl += tv;
    }
    int wtot = __shfl(incl, 63, 64);
    int base = 0;
    if (lane == 63) base = atomicAdd(total, wtot);
    base = __shfl(base, 63, 64);
    int my = base + incl - c;
    if (gid < N) { rowptr[gid] = my; wr[gid] = my; }
}

__global__ void k_scatter(const int* __restrict__ ei, int E,
                          int* __restrict__ wr, int* __restrict__ srcs)
{
    int e = blockIdx.x * BLK + threadIdx.x;
    if (e >= E) return;
    int d = ei[E + e];
    int p = atomicAdd(&wr[d], 1);
    srcs[p] = ei[e];
}

// ---------- layer 0 node precompute: xl = x@Wl+bl, xr = x@Wr+br, res = relu(x@Wres+bres)
__global__ void k_pre0(const float* __restrict__ x,
                       const float* __restrict__ Wl, const float* __restrict__ bl,
                       const float* __restrict__ Wr, const float* __restrict__ br,
                       const float* __restrict__ Wres, const float* __restrict__ bres,
                       float* __restrict__ xl, float* __restrict__ xr, float* __restrict__ res,
                       int N)
{
    int gid = blockIdx.x * BLK + threadIdx.x;
    if (gid >= N * 64) return;
    int n = gid >> 6, c = gid & 63;
    const float* xrow = x + (size_t)n * 16;
    float al = bl[c], ar = br[c], ares = bres[c];
    #pragma unroll
    for (int k = 0; k < 16; ++k) {
        float xv = xrow[k];
        al += xv * Wl[k * 64 + c];
        ar += xv * Wr[k * 64 + c];
        ares += xv * Wres[k * 64 + c];
    }
    xl[gid] = al;
    xr[gid] = ar;
    res[gid] = relu(ares);
}

// ---------- layer 1 node precompute (64->64, no bias on xl/xr) ----------
__global__ void k_pre1(const float* __restrict__ h,
                       const float* __restrict__ Wl, const float* __restrict__ Wr,
                       const float* __restrict__ Wres, const float* __restrict__ bres,
                       float* __restrict__ xl, float* __restrict__ xr, float* __restrict__ res,
                       int N)
{
    int gid = blockIdx.x * BLK + threadIdx.x;
    if (gid >= N * 64) return;
    int n = gid >> 6, c = gid & 63;
    const float* hrow = h + (size_t)n * 64;
    float al = 0.f, ar = 0.f, ares = bres[c];
    #pragma unroll 8
    for (int k = 0; k < 64; ++k) {
        float hv = hrow[k];
        al += hv * Wl[k * 64 + c];
        ar += hv * Wr[k * 64 + c];
        ares += hv * Wres[k * 64 + c];
    }
    xl[gid] = al;
    xr[gid] = ar;
    res[gid] = relu(ares);
}

// ---------- fused GATv2 aggregation: one wave per destination node ----------
// lane c in [0,64): channel c; lanes 0-31 = head 0, lanes 32-63 = head 1.
// Online softmax over incoming edges; self-loop processed first (init).
__global__ void k_gat(const int* __restrict__ rowptr, const int* __restrict__ deg,
                      const int* __restrict__ srcs,
                      const float* __restrict__ xl, const float* __restrict__ xr,
                      const float* __restrict__ att, const float* __restrict__ bias,
                      const float* __restrict__ res,
                      float* __restrict__ hout, int N)
{
    int node = blockIdx.x * (BLK / 64) + (threadIdx.x >> 6);
    if (node >= N) return;
    int c = threadIdx.x & 63;
    float attc = att[c];
    float xrc = xr[(size_t)node * 64 + c];

    // self loop (always present, appended by reference)
    float xlc = xl[(size_t)node * 64 + c];
    float v = leaky02(xlc + xrc) * attc;
    #pragma unroll
    for (int off = 16; off >= 1; off >>= 1) v += __shfl_xor(v, off, 32);
    float m = v;       // running max (this lane's head)
    float den = 1.f;   // exp(v - m)
    float acc = xlc;   // sum of ex * xl over edges

    int beg = rowptr[node];
    int dc = deg[node];
    for (int j = 0; j < dc; ++j) {
        int s = srcs[beg + j];
        float xls = xl[(size_t)s * 64 + c];
        float lv = leaky02(xls + xrc) * attc;
        #pragma unroll
        for (int off = 16; off >= 1; off >>= 1) lv += __shfl_xor(lv, off, 32);
        float mn = fmaxf(m, lv);
        float scale = __expf(m - mn);
        float ex = __expf(lv - mn);
        den = den * scale + ex;
        acc = acc * scale + ex * xls;
        m = mn;
    }

    float hv = acc / den;
    if (bias) hv += bias[c];
    hv = relu(hv) + res[(size_t)node * 64 + c];
    hout[(size_t)node * 64 + c] = hv;
}

// ---------- decoder ----------
__global__ void k_dec(const float* __restrict__ h, const float* __restrict__ cond,
                      const float* __restrict__ wcomb, const float* __restrict__ bfinal,
                      float* __restrict__ out, int N)
{
    int n = blockIdx.x * BLK + threadIdx.x;
    if (n >= N) return;
    float o0 = bfinal[0], o1 = bfinal[1];
    const float* hrow = h + (size_t)n * 64;
    #pragma unroll 8
    for (int c = 0; c < 64; ++c) {
        float hv = hrow[c];
        o0 += hv * wcomb[c * 2];
        o1 += hv * wcomb[c * 2 + 1];
    }
    const float* crow = cond + (size_t)n * 16;
    #pragma unroll
    for (int d = 0; d < 16; ++d) {
        float cv = crow[d];
        o0 += cv * wcomb[(80 + d) * 2];
        o1 += cv * wcomb[(80 + d) * 2 + 1];
    }
    out[(size_t)n * 2] = o0;
    out[(size_t)n * 2 + 1] = o1;
}

static inline int gblk(long long threads) { return (int)((threads + BLK - 1) / BLK); }

extern "C" void kernel_launch(void* const* d_in, const int* in_sizes, int n_in,
                              void* d_out, int out_size, void* d_ws, size_t ws_size,
                              hipStream_t stream) {
    const float* x     = (const float*)d_in[0];
    const int*   ei    = (const int*)d_in[1];
    const int*   t     = (const int*)d_in[2];
    const float* cond  = (const float*)d_in[3];
    const float* Wl0   = (const float*)d_in[4];
    const float* bl0   = (const float*)d_in[5];
    const float* Wr0   = (const float*)d_in[6];
    const float* br0   = (const float*)d_in[7];
    const float* att0  = (const float*)d_in[8];
    const float* bias0 = (const float*)d_in[9];
    const float* Wres0 = (const float*)d_in[10];
    const float* bres0 = (const float*)d_in[11];
    const float* Wl1   = (const float*)d_in[12];
    const float* Wr1   = (const float*)d_in[13];
    const float* att1  = (const float*)d_in[14];
    const float* Wres1 = (const float*)d_in[15];
    const float* bres1 = (const float*)d_in[16];
    const float* Wt0   = (const float*)d_in[17];
    const float* bt0   = (const float*)d_in[18];
    const float* Wt1   = (const float*)d_in[19];
    const float* bt1   = (const float*)d_in[20];
    const float* Wfd   = (const float*)d_in[21];
    const float* bfd   = (const float*)d_in[22];
    const float* Wcls  = (const float*)d_in[23];
    const float* bcls  = (const float*)d_in[24];
    float* out = (float*)d_out;

    const int N  = in_sizes[0] / 16;
    const int E  = in_sizes[1] / 2;

    float* ws = (float*)d_ws;
    size_t o = 0;
    float* xl    = ws + o; o += (size_t)N * 64;
    float* xr    = ws + o; o += (size_t)N * 64;
    float* res   = ws + o; o += (size_t)N * 64;
    float* hbuf  = ws + o; o += (size_t)N * 64;
    float* wcomb = ws + o; o += 192;
    float* bfin  = ws + o; o += 2;
    int* iws     = (int*)(ws + o);
    size_t io = 0;
    int* cnt    = iws + io; io += N;      // degree (excl. self loop)
    int* rowptr = iws + io; io += N;      // segment base
    int* wr     = iws + io; io += N;      // scatter cursor
    int* srcs   = iws + io; io += E;      // src ids grouped by dst
    int* total  = iws + io; io += 1;

    // tiny decoder/time precompute
    k_tiny<<<1, BLK, 0, stream>>>(t, Wt0, bt0, Wt1, bt1, Wfd, bfd, Wcls, bcls, wcomb, bfin);

    // ---- CSR build (edges grouped by destination; self-loops implicit) ----
    k_zero<<<gblk(N), BLK, 0, stream>>>(cnt, total, N);
    k_hist<<<gblk(E), BLK, 0, stream>>>(ei, E, cnt);
    k_base<<<gblk(N), BLK, 0, stream>>>(cnt, rowptr, wr, total, N);
    k_scatter<<<gblk(E), BLK, 0, stream>>>(ei, E, wr, srcs);

    // ---- layer 0 ----
    k_pre0<<<gblk((long long)N * 64), BLK, 0, stream>>>(x, Wl0, bl0, Wr0, br0, Wres0, bres0, xl, xr, res, N);
    k_gat<<<gblk((long long)N * 64), BLK, 0, stream>>>(rowptr, cnt, srcs, xl, xr, att0, bias0, res, hbuf, N);

    // ---- layer 1 ----
    k_pre1<<<gblk((long long)N * 64), BLK, 0, stream>>>(hbuf, Wl1, Wr1, Wres1, bres1, xl, xr, res, N);
    k_gat<<<gblk((long long)N * 64), BLK, 0, stream>>>(rowptr, cnt, srcs, xl, xr, att1, nullptr, res, hbuf, N);

    // ---- decoder ----
    k_dec<<<gblk(N), BLK, 0, stream>>>(hbuf, cond, wcomb, bfin, out, N);
}

// Round 3
// 643.105 us; speedup vs baseline: 2.8631x; 1.3563x over previous
//
#include <hip/hip_runtime.h>
#include <hip/hip_bf16.h>
#include <hip/hip_fp16.h>
#include <math.h>

// Edge_Encoder_Residual: 2-layer GATv2 on line-graph + time-MLP + decoder.
// Round 3: fp16 xl gather tables (half the gather bytes), 4 nodes per wave
// (16 lanes/node, 4 ch/lane, width-8 logit reduce -> 3 shuffle steps, 4x ILP),
// decoder fused into layer-1 epilogue.

#define BLK 256

struct half4 { _Float16 x, y, z, w; };

__device__ __forceinline__ float leaky02(float x) { return x >= 0.f ? x : 0.2f * x; }
__device__ __forceinline__ float relu(float x) { return x > 0.f ? x : 0.f; }

// ---------- tiny: time embedding + MLP + collapsed decoder matrices ----------
__global__ void k_tiny(const int* __restrict__ t,
                       const float* __restrict__ Wt0, const float* __restrict__ bt0,
                       const float* __restrict__ Wt1, const float* __restrict__ bt1,
                       const float* __restrict__ Wfd, const float* __restrict__ bfd,
                       const float* __restrict__ Wcls, const float* __restrict__ bcls,
                       float* __restrict__ wcomb,   // [96][2]
                       float* __restrict__ bfinal)  // [2]
{
    __shared__ float temb[16];
    int tid = threadIdx.x;
    if (tid == 0) {
        float tf = (float)t[0];  // * (1000/MAX_TIME) == *1
        float e0[16], v1[16];
        const float cexp = -logf(10000.f) / 7.f;
        for (int j = 0; j < 8; ++j) {
            float ang = tf * expf((float)j * cexp);
            e0[j] = sinf(ang);
            e0[8 + j] = cosf(ang);
        }
        for (int i = 0; i < 16; ++i) {
            float a = bt0[i];
            for (int j = 0; j < 16; ++j) a += e0[j] * Wt0[j * 16 + i];
            v1[i] = a / (1.f + expf(-a));  // silu
        }
        for (int i = 0; i < 16; ++i) {
            float a = bt1[i];
            for (int j = 0; j < 16; ++j) a += v1[j] * Wt1[j * 16 + i];
            temb[i] = a / (1.f + expf(-a));
        }
    }
    __syncthreads();
    if (tid < 192) {  // wcomb[i][k] = sum_j Wfd[i][j] * Wcls[j][k]
        int i = tid >> 1, k = tid & 1;
        float a = 0.f;
        for (int j = 0; j < 32; ++j) a += Wfd[i * 32 + j] * Wcls[j * 2 + k];
        wcomb[tid] = a;
    }
    __syncthreads();
    if (tid < 2) {  // bias + time contribution (node-constant)
        float a = bcls[tid];
        for (int j = 0; j < 32; ++j) a += bfd[j] * Wcls[j * 2 + tid];
        for (int d = 0; d < 16; ++d) a += temb[d] * wcomb[(64 + d) * 2 + tid];
        bfinal[tid] = a;
    }
}

// ---------- CSR build ----------
__global__ void k_zero(int* __restrict__ cnt, int* __restrict__ total, int N)
{
    int gid = blockIdx.x * BLK + threadIdx.x;
    if (gid < N) cnt[gid] = 0;
    if (gid == 0) *total = 0;
}

__global__ void k_hist(const int* __restrict__ ei, int E, int* __restrict__ cnt)
{
    int e = blockIdx.x * BLK + threadIdx.x;
    if (e < E) atomicAdd(&cnt[ei[E + e]], 1);
}

__global__ void k_base(const int* __restrict__ cnt, int* __restrict__ rowptr,
                       int* __restrict__ wr, int* __restrict__ total, int N)
{
    int gid = blockIdx.x * BLK + threadIdx.x;
    int lane = threadIdx.x & 63;
    int c = (gid < N) ? cnt[gid] : 0;
    int incl = c;
    #pragma unroll
    for (int off = 1; off < 64; off <<= 1) {
        int tv = __shfl_up(incl, off, 64);
        if (lane >= off) incl += tv;
    }
    int wtot = __shfl(incl, 63, 64);
    int base = 0;
    if (lane == 63) base = atomicAdd(total, wtot);
    base = __shfl(base, 63, 64);
    int my = base + incl - c;
    if (gid < N) { rowptr[gid] = my; wr[gid] = my; }
}

__global__ void k_scatter(const int* __restrict__ ei, int E,
                          int* __restrict__ wr, int* __restrict__ srcs)
{
    int e = blockIdx.x * BLK + threadIdx.x;
    if (e >= E) return;
    int d = ei[E + e];
    int p = atomicAdd(&wr[d], 1);
    srcs[p] = ei[e];
}

// ---------- layer 0 node precompute ----------
__global__ void k_pre0(const float* __restrict__ x,
                       const float* __restrict__ Wl, const float* __restrict__ bl,
                       const float* __restrict__ Wr, const float* __restrict__ br,
                       const float* __restrict__ Wres, const float* __restrict__ bres,
                       _Float16* __restrict__ xlh, float* __restrict__ xr, float* __restrict__ res,
                       int N)
{
    int gid = blockIdx.x * BLK + threadIdx.x;
    if (gid >= N * 64) return;
    int n = gid >> 6, c = gid & 63;
    const float* xrow = x + (size_t)n * 16;
    float al = bl[c], ar = br[c], ares = bres[c];
    #pragma unroll
    for (int k = 0; k < 16; ++k) {
        float xv = xrow[k];
        al += xv * Wl[k * 64 + c];
        ar += xv * Wr[k * 64 + c];
        ares += xv * Wres[k * 64 + c];
    }
    xlh[gid] = (_Float16)al;
    xr[gid] = ar;
    res[gid] = relu(ares);
}

// ---------- layer 1 node precompute (64->64, no bias on xl/xr) ----------
__global__ void k_pre1(const float* __restrict__ h,
                       const float* __restrict__ Wl, const float* __restrict__ Wr,
                       const float* __restrict__ Wres, const float* __restrict__ bres,
                       _Float16* __restrict__ xlh, float* __restrict__ xr, float* __restrict__ res,
                       int N)
{
    int gid = blockIdx.x * BLK + threadIdx.x;
    if (gid >= N * 64) return;
    int n = gid >> 6, c = gid & 63;
    const float* hrow = h + (size_t)n * 64;
    float al = 0.f, ar = 0.f, ares = bres[c];
    #pragma unroll 8
    for (int k = 0; k < 64; ++k) {
        float hv = hrow[k];
        al += hv * Wl[k * 64 + c];
        ar += hv * Wr[k * 64 + c];
        ares += hv * Wres[k * 64 + c];
    }
    xlh[gid] = (_Float16)al;
    xr[gid] = ar;
    res[gid] = relu(ares);
}

// ---------- fused GATv2 aggregation: 4 nodes per wave ----------
// lane l: group g = l>>4 (node), q = l&15; lane handles channels 4q..4q+3.
// q 0-7 -> head 0 (ch 0-31), q 8-15 -> head 1 (ch 32-63).
// Online softmax per node; self-loop initializes (m, den=1, acc=xl_self).
// DEC: fuse decoder (out[n][2]) instead of writing hout.
template <bool DEC>
__global__ void k_gat2(const int* __restrict__ rowptr, const int* __restrict__ deg,
                       const int* __restrict__ srcs,
                       const _Float16* __restrict__ xlh, const float* __restrict__ xr,
                       const float* __restrict__ att, const float* __restrict__ bias,
                       const float* __restrict__ res,
                       float* __restrict__ hout,
                       const float* __restrict__ cond, const float* __restrict__ wcomb,
                       const float* __restrict__ bfinal, float* __restrict__ out,
                       int N)
{
    int l = threadIdx.x & 63;
    int g = l >> 4, q = l & 15;
    int node = blockIdx.x * 16 + (threadIdx.x >> 6) * 4 + g;
    bool nvalid = node < N;
    int n = nvalid ? node : 0;

    float4 a4 = *(const float4*)(att + q * 4);
    float4 xr4 = *(const float4*)(xr + (size_t)n * 64 + q * 4);

    // self loop
    half4 hs = *(const half4*)(xlh + (size_t)n * 64 + q * 4);
    float s0 = (float)hs.x, s1 = (float)hs.y, s2 = (float)hs.z, s3 = (float)hs.w;
    float lv = leaky02(s0 + xr4.x) * a4.x + leaky02(s1 + xr4.y) * a4.y
             + leaky02(s2 + xr4.z) * a4.z + leaky02(s3 + xr4.w) * a4.w;
    lv += __shfl_xor(lv, 1, 8);
    lv += __shfl_xor(lv, 2, 8);
    lv += __shfl_xor(lv, 4, 8);

    float m = lv, den = 1.f;
    float ac0 = s0, ac1 = s1, ac2 = s2, ac3 = s3;

    int dg = nvalid ? deg[n] : 0;
    int beg = nvalid ? rowptr[n] : 0;

    for (int j = 0;; ++j) {
        bool act = j < dg;
        if (!__any(act)) break;
        int s = srcs[act ? beg + j : 0];
        half4 hx = *(const half4*)(xlh + (size_t)s * 64 + q * 4);
        float x0 = (float)hx.x, x1 = (float)hx.y, x2 = (float)hx.z, x3 = (float)hx.w;
        float e = leaky02(x0 + xr4.x) * a4.x + leaky02(x1 + xr4.y) * a4.y
                + leaky02(x2 + xr4.z) * a4.z + leaky02(x3 + xr4.w) * a4.w;
        e += __shfl_xor(e, 1, 8);
        e += __shfl_xor(e, 2, 8);
        e += __shfl_xor(e, 4, 8);
        if (!act) e = -1e30f;
        float mn = fmaxf(m, e);
        float sc = __expf(m - mn);
        float ex = __expf(e - mn);
        den = den * sc + ex;
        ac0 = ac0 * sc + ex * x0;
        ac1 = ac1 * sc + ex * x1;
        ac2 = ac2 * sc + ex * x2;
        ac3 = ac3 * sc + ex * x3;
        m = mn;
    }

    float inv = 1.f / den;
    float4 r4 = *(const float4*)(res + (size_t)n * 64 + q * 4);
    float h0, h1, h2, h3;
    if (bias) {
        const float4 b4 = *(const float4*)(bias + q * 4);
        h0 = relu(ac0 * inv + b4.x) + r4.x;
        h1 = relu(ac1 * inv + b4.y) + r4.y;
        h2 = relu(ac2 * inv + b4.z) + r4.z;
        h3 = relu(ac3 * inv + b4.w) + r4.w;
    } else {
        h0 = relu(ac0 * inv) + r4.x;
        h1 = relu(ac1 * inv) + r4.y;
        h2 = relu(ac2 * inv) + r4.z;
        h3 = relu(ac3 * inv) + r4.w;
    }

    if (!DEC) {
        if (nvalid) {
            float4 o; o.x = h0; o.y = h1; o.z = h2; o.w = h3;
            *(float4*)(hout + (size_t)n * 64 + q * 4) = o;
        }
    } else {
        // decoder: out[n][k] = sum_c h_c*wcomb[c][k] + sum_d cond_d*wcomb[80+d][k] + bfinal[k]
        int c0 = q * 4;
        float p0 = h0 * wcomb[(c0 + 0) * 2] + h1 * wcomb[(c0 + 1) * 2]
                 + h2 * wcomb[(c0 + 2) * 2] + h3 * wcomb[(c0 + 3) * 2];
        float p1 = h0 * wcomb[(c0 + 0) * 2 + 1] + h1 * wcomb[(c0 + 1) * 2 + 1]
                 + h2 * wcomb[(c0 + 2) * 2 + 1] + h3 * wcomb[(c0 + 3) * 2 + 1];
        if (q < 4) {
            float4 c4 = *(const float4*)(cond + (size_t)n * 16 + q * 4);
            int d0 = 80 + q * 4;
            p0 += c4.x * wcomb[(d0 + 0) * 2] + c4.y * wcomb[(d0 + 1) * 2]
                + c4.z * wcomb[(d0 + 2) * 2] + c4.w * wcomb[(d0 + 3) * 2];
            p1 += c4.x * wcomb[(d0 + 0) * 2 + 1] + c4.y * wcomb[(d0 + 1) * 2 + 1]
                + c4.z * wcomb[(d0 + 2) * 2 + 1] + c4.w * wcomb[(d0 + 3) * 2 + 1];
        }
        #pragma unroll
        for (int off = 1; off < 16; off <<= 1) {
            p0 += __shfl_xor(p0, off, 16);
            p1 += __shfl_xor(p1, off, 16);
        }
        if (q == 0 && nvalid) {
            out[(size_t)n * 2] = p0 + bfinal[0];
            out[(size_t)n * 2 + 1] = p1 + bfinal[1];
        }
    }
}

static inline int gblk(long long threads) { return (int)((threads + BLK - 1) / BLK); }

extern "C" void kernel_launch(void* const* d_in, const int* in_sizes, int n_in,
                              void* d_out, int out_size, void* d_ws, size_t ws_size,
                              hipStream_t stream) {
    const float* x     = (const float*)d_in[0];
    const int*   ei    = (const int*)d_in[1];
    const int*   t     = (const int*)d_in[2];
    const float* cond  = (const float*)d_in[3];
    const float* Wl0   = (const float*)d_in[4];
    const float* bl0   = (const float*)d_in[5];
    const float* Wr0   = (const float*)d_in[6];
    const float* br0   = (const float*)d_in[7];
    const float* att0  = (const float*)d_in[8];
    const float* bias0 = (const float*)d_in[9];
    const float* Wres0 = (const float*)d_in[10];
    const float* bres0 = (const float*)d_in[11];
    const float* Wl1   = (const float*)d_in[12];
    const float* Wr1   = (const float*)d_in[13];
    const float* att1  = (const float*)d_in[14];
    const float* Wres1 = (const float*)d_in[15];
    const float* bres1 = (const float*)d_in[16];
    const float* Wt0   = (const float*)d_in[17];
    const float* bt0   = (const float*)d_in[18];
    const float* Wt1   = (const float*)d_in[19];
    const float* bt1   = (const float*)d_in[20];
    const float* Wfd   = (const float*)d_in[21];
    const float* bfd   = (const float*)d_in[22];
    const float* Wcls  = (const float*)d_in[23];
    const float* bcls  = (const float*)d_in[24];
    float* out = (float*)d_out;

    const int N  = in_sizes[0] / 16;
    const int E  = in_sizes[1] / 2;

    float* ws = (float*)d_ws;
    size_t o = 0;
    float* xr    = ws + o; o += (size_t)N * 64;
    float* res   = ws + o; o += (size_t)N * 64;
    float* hbuf  = ws + o; o += (size_t)N * 64;
    float* wcomb = ws + o; o += 192;
    float* bfin  = ws + o; o += 2;
    _Float16* xlh = (_Float16*)(ws + o); o += (size_t)N * 32;  // N*64 halves
    int* iws     = (int*)(ws + o);
    size_t io = 0;
    int* cnt    = iws + io; io += N;      // degree (excl. self loop)
    int* rowptr = iws + io; io += N;      // segment base
    int* wr     = iws + io; io += N;      // scatter cursor
    int* srcs   = iws + io; io += E;      // src ids grouped by dst
    int* total  = iws + io; io += 1;

    // tiny decoder/time precompute
    k_tiny<<<1, BLK, 0, stream>>>(t, Wt0, bt0, Wt1, bt1, Wfd, bfd, Wcls, bcls, wcomb, bfin);

    // ---- CSR build (edges grouped by destination; self-loops implicit) ----
    k_zero<<<gblk(N), BLK, 0, stream>>>(cnt, total, N);
    k_hist<<<gblk(E), BLK, 0, stream>>>(ei, E, cnt);
    k_base<<<gblk(N), BLK, 0, stream>>>(cnt, rowptr, wr, total, N);
    k_scatter<<<gblk(E), BLK, 0, stream>>>(ei, E, wr, srcs);

    const int gatBlocks = (N + 15) / 16;

    // ---- layer 0 ----
    k_pre0<<<gblk((long long)N * 64), BLK, 0, stream>>>(x, Wl0, bl0, Wr0, br0, Wres0, bres0, xlh, xr, res, N);
    k_gat2<false><<<gatBlocks, BLK, 0, stream>>>(rowptr, cnt, srcs, xlh, xr, att0, bias0, res,
                                                 hbuf, nullptr, nullptr, nullptr, nullptr, N);

    // ---- layer 1 (decoder fused) ----
    k_pre1<<<gblk((long long)N * 64), BLK, 0, stream>>>(hbuf, Wl1, Wr1, Wres1, bres1, xlh, xr, res, N);
    k_gat2<true><<<gatBlocks, BLK, 0, stream>>>(rowptr, cnt, srcs, xlh, xr, att1, nullptr, res,
                                                nullptr, cond, wcomb, bfin, out, N);
}

// Round 4
// 546.261 us; speedup vs baseline: 3.3707x; 1.1773x over previous
//
#include <hip/hip_runtime.h>
#include <hip/hip_bf16.h>
#include <hip/hip_fp16.h>
#include <math.h>

// Edge_Encoder_Residual: 2-layer GATv2 on line-graph + time-MLP + decoder.
// Round 4: (1) pre0/pre1 rewritten as 8-nodes-per-wave register-blocked
// matmuls (shfl-broadcast h, 24-acc ILP); (2) gat2 gather uses properly
// aligned ext_vector half4 (single dwordx2) + 1-deep software prefetch and
// wave-uniform loop bound; (3) xlh 16B-aligned in the workspace arena.

#define BLK 256

typedef _Float16 half4v __attribute__((ext_vector_type(4)));

__device__ __forceinline__ float leaky02(float x) { return x >= 0.f ? x : 0.2f * x; }
__device__ __forceinline__ float relu(float x) { return x > 0.f ? x : 0.f; }

// ---------- tiny: time embedding + MLP + collapsed decoder matrices ----------
__global__ void k_tiny(const int* __restrict__ t,
                       const float* __restrict__ Wt0, const float* __restrict__ bt0,
                       const float* __restrict__ Wt1, const float* __restrict__ bt1,
                       const float* __restrict__ Wfd, const float* __restrict__ bfd,
                       const float* __restrict__ Wcls, const float* __restrict__ bcls,
                       float* __restrict__ wcomb,   // [96][2]
                       float* __restrict__ bfinal)  // [2]
{
    __shared__ float temb[16];
    int tid = threadIdx.x;
    if (tid == 0) {
        float tf = (float)t[0];  // * (1000/MAX_TIME) == *1
        float e0[16], v1[16];
        const float cexp = -logf(10000.f) / 7.f;
        for (int j = 0; j < 8; ++j) {
            float ang = tf * expf((float)j * cexp);
            e0[j] = sinf(ang);
            e0[8 + j] = cosf(ang);
        }
        for (int i = 0; i < 16; ++i) {
            float a = bt0[i];
            for (int j = 0; j < 16; ++j) a += e0[j] * Wt0[j * 16 + i];
            v1[i] = a / (1.f + expf(-a));  // silu
        }
        for (int i = 0; i < 16; ++i) {
            float a = bt1[i];
            for (int j = 0; j < 16; ++j) a += v1[j] * Wt1[j * 16 + i];
            temb[i] = a / (1.f + expf(-a));
        }
    }
    __syncthreads();
    if (tid < 192) {  // wcomb[i][k] = sum_j Wfd[i][j] * Wcls[j][k]
        int i = tid >> 1, k = tid & 1;
        float a = 0.f;
        for (int j = 0; j < 32; ++j) a += Wfd[i * 32 + j] * Wcls[j * 2 + k];
        wcomb[tid] = a;
    }
    __syncthreads();
    if (tid < 2) {  // bias + time contribution (node-constant)
        float a = bcls[tid];
        for (int j = 0; j < 32; ++j) a += bfd[j] * Wcls[j * 2 + tid];
        for (int d = 0; d < 16; ++d) a += temb[d] * wcomb[(64 + d) * 2 + tid];
        bfinal[tid] = a;
    }
}

// ---------- CSR build ----------
__global__ void k_zero(int* __restrict__ cnt, int* __restrict__ total, int N)
{
    int gid = blockIdx.x * BLK + threadIdx.x;
    if (gid < N) cnt[gid] = 0;
    if (gid == 0) *total = 0;
}

__global__ void k_hist(const int* __restrict__ ei, int E, int* __restrict__ cnt)
{
    int e = blockIdx.x * BLK + threadIdx.x;
    if (e < E) atomicAdd(&cnt[ei[E + e]], 1);
}

__global__ void k_base(const int* __restrict__ cnt, int* __restrict__ rowptr,
                       int* __restrict__ wr, int* __restrict__ total, int N)
{
    int gid = blockIdx.x * BLK + threadIdx.x;
    int lane = threadIdx.x & 63;
    int c = (gid < N) ? cnt[gid] : 0;
    int incl = c;
    #pragma unroll
    for (int off = 1; off < 64; off <<= 1) {
        int tv = __shfl_up(incl, off, 64);
        if (lane >= off) incl += tv;
    }
    int wtot = __shfl(incl, 63, 64);
    int base = 0;
    if (lane == 63) base = atomicAdd(total, wtot);
    base = __shfl(base, 63, 64);
    int my = base + incl - c;
    if (gid < N) { rowptr[gid] = my; wr[gid] = my; }
}

__global__ void k_scatter(const int* __restrict__ ei, int E,
                          int* __restrict__ wr, int* __restrict__ srcs)
{
    int e = blockIdx.x * BLK + threadIdx.x;
    if (e >= E) return;
    int d = ei[E + e];
    int p = atomicAdd(&wr[d], 1);
    srcs[p] = ei[e];
}

// ---------- layer 0 node precompute: 8 nodes per wave, lane = channel ----------
__global__ void k_pre0v(const float* __restrict__ x,
                        const float* __restrict__ Wl, const float* __restrict__ bl,
                        const float* __restrict__ Wr, const float* __restrict__ br,
                        const float* __restrict__ Wres, const float* __restrict__ bres,
                        _Float16* __restrict__ xlh, float* __restrict__ xr, float* __restrict__ res,
                        int N)
{
    int wid = (int)(((long long)blockIdx.x * BLK + threadIdx.x) >> 6);
    int c = threadIdx.x & 63;
    int n0 = wid * 8;
    if (n0 >= N) return;
    // lane c holds x[n0 + (c>>4)][c&15] and x[n0+4+(c>>4)][c&15]
    int ra_n = n0 + (c >> 4);     if (ra_n >= N) ra_n = N - 1;
    int rb_n = n0 + 4 + (c >> 4); if (rb_n >= N) rb_n = N - 1;
    float ra = x[(size_t)ra_n * 16 + (c & 15)];
    float rb = x[(size_t)rb_n * 16 + (c & 15)];

    float al[8], ar[8], as[8];
    float vbl = bl[c], vbr = br[c], vbs = bres[c];
    #pragma unroll
    for (int i = 0; i < 8; ++i) { al[i] = vbl; ar[i] = vbr; as[i] = vbs; }
    #pragma unroll
    for (int k = 0; k < 16; ++k) {
        float wl = Wl[k * 64 + c], wr_ = Wr[k * 64 + c], ws = Wres[k * 64 + c];
        #pragma unroll
        for (int i = 0; i < 8; ++i) {
            float hv = __shfl(i < 4 ? ra : rb, ((i & 3) << 4) | k, 64);
            al[i] = fmaf(hv, wl, al[i]);
            ar[i] = fmaf(hv, wr_, ar[i]);
            as[i] = fmaf(hv, ws, as[i]);
        }
    }
    #pragma unroll
    for (int i = 0; i < 8; ++i) {
        int n = n0 + i;
        if (n < N) {
            xlh[(size_t)n * 64 + c] = (_Float16)al[i];
            xr[(size_t)n * 64 + c]  = ar[i];
            res[(size_t)n * 64 + c] = relu(as[i]);
        }
    }
}

// ---------- layer 1 node precompute: 8 nodes per wave ----------
__global__ void k_pre1v(const float* __restrict__ h,
                        const float* __restrict__ Wl, const float* __restrict__ Wr,
                        const float* __restrict__ Wres, const float* __restrict__ bres,
                        _Float16* __restrict__ xlh, float* __restrict__ xr, float* __restrict__ res,
                        int N)
{
    int wid = (int)(((long long)blockIdx.x * BLK + threadIdx.x) >> 6);
    int c = threadIdx.x & 63;
    int n0 = wid * 8;
    if (n0 >= N) return;
    float hreg[8];
    #pragma unroll
    for (int i = 0; i < 8; ++i) {
        int n = n0 + i; if (n >= N) n = N - 1;
        hreg[i] = h[(size_t)n * 64 + c];
    }
    float al[8], ar[8], as[8];
    float vbs = bres[c];
    #pragma unroll
    for (int i = 0; i < 8; ++i) { al[i] = 0.f; ar[i] = 0.f; as[i] = vbs; }
    #pragma unroll 4
    for (int k = 0; k < 64; ++k) {
        float wl = Wl[k * 64 + c], wr_ = Wr[k * 64 + c], ws = Wres[k * 64 + c];
        #pragma unroll
        for (int i = 0; i < 8; ++i) {
            float hv = __shfl(hreg[i], k, 64);
            al[i] = fmaf(hv, wl, al[i]);
            ar[i] = fmaf(hv, wr_, ar[i]);
            as[i] = fmaf(hv, ws, as[i]);
        }
    }
    #pragma unroll
    for (int i = 0; i < 8; ++i) {
        int n = n0 + i;
        if (n < N) {
            xlh[(size_t)n * 64 + c] = (_Float16)al[i];
            xr[(size_t)n * 64 + c]  = ar[i];
            res[(size_t)n * 64 + c] = relu(as[i]);
        }
    }
}

// ---------- fused GATv2 aggregation: 4 nodes per wave, prefetched gather ----------
// lane l: group g = l>>4 (node), q = l&15; lane handles channels 4q..4q+3.
// q 0-7 -> head 0, q 8-15 -> head 1. Online softmax; self-loop initializes.
template <bool DEC>
__global__ void k_gat2(const int* __restrict__ rowptr, const int* __restrict__ deg,
                       const int* __restrict__ srcs,
                       const _Float16* __restrict__ xlh, const float* __restrict__ xr,
                       const float* __restrict__ att, const float* __restrict__ bias,
                       const float* __restrict__ res,
                       float* __restrict__ hout,
                       const float* __restrict__ cond, const float* __restrict__ wcomb,
                       const float* __restrict__ bfinal, float* __restrict__ out,
                       int N)
{
    int l = threadIdx.x & 63;
    int g = l >> 4, q = l & 15;
    int node = blockIdx.x * 16 + (threadIdx.x >> 6) * 4 + g;
    bool nvalid = node < N;
    int n = nvalid ? node : 0;

    float4 a4 = *(const float4*)(att + q * 4);
    float4 xr4 = *(const float4*)(xr + (size_t)n * 64 + q * 4);

    // self loop
    half4v hs = *(const half4v*)(xlh + (size_t)n * 64 + q * 4);
    float s0 = (float)hs.x, s1 = (float)hs.y, s2 = (float)hs.z, s3 = (float)hs.w;
    float lv = leaky02(s0 + xr4.x) * a4.x + leaky02(s1 + xr4.y) * a4.y
             + leaky02(s2 + xr4.z) * a4.z + leaky02(s3 + xr4.w) * a4.w;
    lv += __shfl_xor(lv, 1, 8);
    lv += __shfl_xor(lv, 2, 8);
    lv += __shfl_xor(lv, 4, 8);

    float m = lv, den = 1.f;
    float ac0 = s0, ac1 = s1, ac2 = s2, ac3 = s3;

    int dg = nvalid ? deg[n] : 0;
    int beg = nvalid ? rowptr[n] : 0;
    int safebeg = (dg > 0) ? beg : 0;

    // wave-uniform loop bound (max deg over the wave's 4 groups)
    int t1 = max(dg, __shfl_xor(dg, 16, 64));
    int wavemax = max(t1, __shfl_xor(t1, 32, 64));

    // 1-deep prefetch
    int s_nxt = srcs[safebeg];
    half4v h_nxt = *(const half4v*)(xlh + (size_t)s_nxt * 64 + q * 4);

    for (int j = 0; j < wavemax; ++j) {
        bool act = j < dg;
        half4v hx = h_nxt;
        int jn = j + 1;
        int pn = (jn < dg) ? beg + jn : safebeg;
        int s2i = srcs[pn];
        h_nxt = *(const half4v*)(xlh + (size_t)s2i * 64 + q * 4);

        float x0 = (float)hx.x, x1 = (float)hx.y, x2 = (float)hx.z, x3 = (float)hx.w;
        float e = leaky02(x0 + xr4.x) * a4.x + leaky02(x1 + xr4.y) * a4.y
                + leaky02(x2 + xr4.z) * a4.z + leaky02(x3 + xr4.w) * a4.w;
        e += __shfl_xor(e, 1, 8);
        e += __shfl_xor(e, 2, 8);
        e += __shfl_xor(e, 4, 8);
        if (!act) e = -1e30f;
        float mn = fmaxf(m, e);
        float sc = __expf(m - mn);
        float ex = __expf(e - mn);
        den = den * sc + ex;
        ac0 = ac0 * sc + ex * x0;
        ac1 = ac1 * sc + ex * x1;
        ac2 = ac2 * sc + ex * x2;
        ac3 = ac3 * sc + ex * x3;
        m = mn;
    }

    float inv = 1.f / den;
    float4 r4 = *(const float4*)(res + (size_t)n * 64 + q * 4);
    float h0, h1, h2, h3;
    if (bias) {
        const float4 b4 = *(const float4*)(bias + q * 4);
        h0 = relu(ac0 * inv + b4.x) + r4.x;
        h1 = relu(ac1 * inv + b4.y) + r4.y;
        h2 = relu(ac2 * inv + b4.z) + r4.z;
        h3 = relu(ac3 * inv + b4.w) + r4.w;
    } else {
        h0 = relu(ac0 * inv) + r4.x;
        h1 = relu(ac1 * inv) + r4.y;
        h2 = relu(ac2 * inv) + r4.z;
        h3 = relu(ac3 * inv) + r4.w;
    }

    if (!DEC) {
        if (nvalid) {
            float4 o; o.x = h0; o.y = h1; o.z = h2; o.w = h3;
            *(float4*)(hout + (size_t)n * 64 + q * 4) = o;
        }
    } else {
        int c0 = q * 4;
        float p0 = h0 * wcomb[(c0 + 0) * 2] + h1 * wcomb[(c0 + 1) * 2]
                 + h2 * wcomb[(c0 + 2) * 2] + h3 * wcomb[(c0 + 3) * 2];
        float p1 = h0 * wcomb[(c0 + 0) * 2 + 1] + h1 * wcomb[(c0 + 1) * 2 + 1]
                 + h2 * wcomb[(c0 + 2) * 2 + 1] + h3 * wcomb[(c0 + 3) * 2 + 1];
        if (q < 4) {
            float4 c4 = *(const float4*)(cond + (size_t)n * 16 + q * 4);
            int d0 = 80 + q * 4;
            p0 += c4.x * wcomb[(d0 + 0) * 2] + c4.y * wcomb[(d0 + 1) * 2]
                + c4.z * wcomb[(d0 + 2) * 2] + c4.w * wcomb[(d0 + 3) * 2];
            p1 += c4.x * wcomb[(d0 + 0) * 2 + 1] + c4.y * wcomb[(d0 + 1) * 2 + 1]
                + c4.z * wcomb[(d0 + 2) * 2 + 1] + c4.w * wcomb[(d0 + 3) * 2 + 1];
        }
        #pragma unroll
        for (int off = 1; off < 16; off <<= 1) {
            p0 += __shfl_xor(p0, off, 16);
            p1 += __shfl_xor(p1, off, 16);
        }
        if (q == 0 && nvalid) {
            out[(size_t)n * 2] = p0 + bfinal[0];
            out[(size_t)n * 2 + 1] = p1 + bfinal[1];
        }
    }
}

static inline int gblk(long long threads) { return (int)((threads + BLK - 1) / BLK); }

extern "C" void kernel_launch(void* const* d_in, const int* in_sizes, int n_in,
                              void* d_out, int out_size, void* d_ws, size_t ws_size,
                              hipStream_t stream) {
    const float* x     = (const float*)d_in[0];
    const int*   ei    = (const int*)d_in[1];
    const int*   t     = (const int*)d_in[2];
    const float* cond  = (const float*)d_in[3];
    const float* Wl0   = (const float*)d_in[4];
    const float* bl0   = (const float*)d_in[5];
    const float* Wr0   = (const float*)d_in[6];
    const float* br0   = (const float*)d_in[7];
    const float* att0  = (const float*)d_in[8];
    const float* bias0 = (const float*)d_in[9];
    const float* Wres0 = (const float*)d_in[10];
    const float* bres0 = (const float*)d_in[11];
    const float* Wl1   = (const float*)d_in[12];
    const float* Wr1   = (const float*)d_in[13];
    const float* att1  = (const float*)d_in[14];
    const float* Wres1 = (const float*)d_in[15];
    const float* bres1 = (const float*)d_in[16];
    const float* Wt0   = (const float*)d_in[17];
    const float* bt0   = (const float*)d_in[18];
    const float* Wt1   = (const float*)d_in[19];
    const float* bt1   = (const float*)d_in[20];
    const float* Wfd   = (const float*)d_in[21];
    const float* bfd   = (const float*)d_in[22];
    const float* Wcls  = (const float*)d_in[23];
    const float* bcls  = (const float*)d_in[24];
    float* out = (float*)d_out;

    const int N  = in_sizes[0] / 16;
    const int E  = in_sizes[1] / 2;

    float* ws = (float*)d_ws;
    size_t o = 0;
    float* xr    = ws + o; o += (size_t)N * 64;   // 16B-aligned blocks (N*64 floats)
    float* res   = ws + o; o += (size_t)N * 64;
    float* hbuf  = ws + o; o += (size_t)N * 64;
    _Float16* xlh = (_Float16*)(ws + o); o += (size_t)N * 32;  // 16B-aligned
    float* wcomb = ws + o; o += 192;
    float* bfin  = ws + o; o += 2;
    int* iws     = (int*)(ws + o);
    size_t io = 0;
    int* cnt    = iws + io; io += N;      // degree (excl. self loop)
    int* rowptr = iws + io; io += N;      // segment base
    int* wr     = iws + io; io += N;      // scatter cursor
    int* srcs   = iws + io; io += E;      // src ids grouped by dst
    int* total  = iws + io; io += 1;

    // tiny decoder/time precompute
    k_tiny<<<1, BLK, 0, stream>>>(t, Wt0, bt0, Wt1, bt1, Wfd, bfd, Wcls, bcls, wcomb, bfin);

    // ---- CSR build (edges grouped by destination; self-loops implicit) ----
    k_zero<<<gblk(N), BLK, 0, stream>>>(cnt, total, N);
    k_hist<<<gblk(E), BLK, 0, stream>>>(ei, E, cnt);
    k_base<<<gblk(N), BLK, 0, stream>>>(cnt, rowptr, wr, total, N);
    k_scatter<<<gblk(E), BLK, 0, stream>>>(ei, E, wr, srcs);

    const long long preThreads = (long long)((N + 7) / 8) * 64;
    const int gatBlocks = (N + 15) / 16;

    // ---- layer 0 ----
    k_pre0v<<<gblk(preThreads), BLK, 0, stream>>>(x, Wl0, bl0, Wr0, br0, Wres0, bres0, xlh, xr, res, N);
    k_gat2<false><<<gatBlocks, BLK, 0, stream>>>(rowptr, cnt, srcs, xlh, xr, att0, bias0, res,
                                                 hbuf, nullptr, nullptr, nullptr, nullptr, N);

    // ---- layer 1 (decoder fused) ----
    k_pre1v<<<gblk(preThreads), BLK, 0, stream>>>(hbuf, Wl1, Wr1, Wres1, bres1, xlh, xr, res, N);
    k_gat2<true><<<gatBlocks, BLK, 0, stream>>>(rowptr, cnt, srcs, xlh, xr, att1, nullptr, res,
                                                nullptr, cond, wcomb, bfin, out, N);
}